// Round 5
// baseline (139.917 us; speedup 1.0000x reference)
//
#include <hip/hip_runtime.h>
#include <stdint.h>

#define S_LEN 4096
#define EMB   1024
#define HEAD  64

typedef short bf16x8 __attribute__((ext_vector_type(8)));
typedef float f32x4  __attribute__((ext_vector_type(4)));
typedef float f32x16 __attribute__((ext_vector_type(16)));
typedef unsigned short ushort8 __attribute__((ext_vector_type(8)));

// scale = 1/sqrt(64) = 0.125, folded with log2(e) so softmax uses exp2
#define QSCALE 0.18033688011112042f

__device__ __forceinline__ unsigned short f2bf(float f) {
    union { float f; uint32_t u; } v; v.f = f;
    uint32_t r = v.u + 0x7fffu + ((v.u >> 16) & 1u);
    return (unsigned short)(r >> 16);
}

// pack two f32 -> one u32 of 2x bf16 (RNE), gfx950 HW op (no builtin)
__device__ __forceinline__ int cvtpk_bf16(float lo, float hi_) {
    int r;
    asm("v_cvt_pk_bf16_f32 %0, %1, %2" : "=v"(r) : "v"(lo), "v"(hi_));
    return r;
}

// async global->LDS, 16B per lane.  LDS dest is wave-uniform base + lane*16;
// global src is per-lane (m104).  size must be a literal.
__device__ __forceinline__ void gload_lds16(const void* g, void* l) {
    __builtin_amdgcn_global_load_lds(
        (const __attribute__((address_space(1))) void*)g,
        (__attribute__((address_space(3))) void*)l, 16, 0, 0);
}

// ---------------------------------------------------------------------------
// Fragment-blocked layouts (R4, kept -- the -19us win):
//   Qp/Kp : [s/32][8 d-chunks][32 rows][8 d]   (2048 shorts per s-block)
//   Vt    : [b][s/8][64 d][8 keys]             (512 shorts per s-group)
// Every flash-side fragment load is two dense 512B segments.
// ---------------------------------------------------------------------------

// ---------------------------------------------------------------------------
// Kernel 0: W prep (unchanged).  wt = 16 per-kchunk linear LDS images,
// XOR-swizzled for qkv's global_load_lds + swizzled ds_read_b128.
// ---------------------------------------------------------------------------
__global__ void wprep_kernel(const float* __restrict__ Wq,
                             const float* __restrict__ Wk,
                             const float* __restrict__ Wv,
                             unsigned short* __restrict__ wt) {
    __shared__ float t[64][65];
    const int tid = threadIdx.x;
    const int m   = blockIdx.x >> 4;
    const int kcb = blockIdx.x & 15;
    const int k0  = kcb << 6;
    const float* W = (m == 0) ? Wq : (m == 1) ? Wk : Wv;
    for (int i = 0; i < 4; ++i) {
        const int k  = (tid >> 4) + i * 16;
        const int n4 = (tid & 15) << 2;
        float4 v = *(const float4*)&W[(k0 + k) * 64 + n4];
        t[k][n4 + 0] = v.x; t[k][n4 + 1] = v.y;
        t[k][n4 + 2] = v.z; t[k][n4 + 3] = v.w;
    }
    __syncthreads();
    const int n = tid >> 2, kq = (tid & 3) << 4;   // 16 k-values per thread
    __align__(16) unsigned short u[16];
    for (int i = 0; i < 16; ++i) u[i] = f2bf(t[kq + i][n]);
    const int nimg = m * 64 + n;
    const int base = kcb * 12288 + nimg * 64;      // shorts
    const int c0   = (kq >> 3) ^ (n & 7);          // swizzled 16B-chunk idx
    const int c1   = ((kq >> 3) + 1) ^ (n & 7);
    *(int4*)&wt[base + c0 * 8] = *(int4*)&u[0];
    *(int4*)&wt[base + c1 * 8] = *(int4*)&u[8];
}

// ---------------------------------------------------------------------------
// Kernel 1: fused QKV projection, bf16 MFMA GEMM.
//   THIS ROUND: wave tiling 4m-wn -> 2m x 4n (wave owns 32 rows x 48 cols):
//   per kk the wave reads 2 A + 3 B ds_read_b128 for 6 MFMA (was 1+6 for 6)
//   -> 10 reads/chunk vs 14, cutting the LDS-read-throughput bound ~29%.
//   Same acc count (6 f32x4), same LDS buffers, same epilogue math.
// ---------------------------------------------------------------------------
__global__ __launch_bounds__(512, 2) void qkv_kernel(
    const float* __restrict__ x, const unsigned short* __restrict__ wt,
    const float* __restrict__ bq, const float* __restrict__ bk,
    const float* __restrict__ bv,
    unsigned short* __restrict__ Qp, unsigned short* __restrict__ Kp,
    unsigned short* __restrict__ Vt) {

    __shared__ __align__(16) unsigned short xs[2][64 * 72];   // 18.4 KB
    __shared__ __align__(16) unsigned short ws[2][12288];     // 49.2 KB

    const int tid  = threadIdx.x;
    const int lane = tid & 63;
    const int w    = tid >> 6;        // 0..7
    const int wm   = w & 1;           // 0..1  (32-row half)
    const int wn   = w >> 1;          // 0..3  (48-col strip)
    const int quad = lane >> 4;
    const int lid  = lane & 15;
    const int row0 = blockIdx.x * 64;

    f32x4 acc[2][3];
    for (int mf = 0; mf < 2; ++mf)
        for (int nf = 0; nf < 3; ++nf) acc[mf][nf] = (f32x4){0.f, 0.f, 0.f, 0.f};

#define STAGE(BUF, KC)                                                         \
    do {                                                                       \
        {   /* x: 64 rows x 64 k fp32 -> bf16, 8 floats per thread */          \
            int rr = tid >> 3, c8 = (tid & 7) << 3;                            \
            const float* xp = &x[(row0 + rr) * EMB + (KC) * 64 + c8];          \
            float4 v0 = *(const float4*)xp;                                    \
            float4 v1 = *(const float4*)(xp + 4);                              \
            ushort8 u;                                                         \
            u[0] = f2bf(v0.x); u[1] = f2bf(v0.y);                              \
            u[2] = f2bf(v0.z); u[3] = f2bf(v0.w);                              \
            u[4] = f2bf(v1.x); u[5] = f2bf(v1.y);                              \
            u[6] = f2bf(v1.z); u[7] = f2bf(v1.w);                              \
            *(ushort8*)&xs[BUF][rr * 72 + c8] = u;                             \
        }                                                                      \
        {   /* wt chunk: 24.6 KB linear swizzled image, 3 KB per wave */       \
            const unsigned short* gs = &wt[(KC) * 12288 + w * 1536 + lane * 8];\
            gload_lds16(gs,        &ws[BUF][w * 1536]);                        \
            gload_lds16(gs +  512, &ws[BUF][w * 1536 +  512]);                 \
            gload_lds16(gs + 1024, &ws[BUF][w * 1536 + 1024]);                 \
        }                                                                      \
    } while (0)

    STAGE(0, 0);
    __syncthreads();

    for (int kc = 0; kc < 16; ++kc) {
        const int cur = kc & 1;
        if (kc + 1 < 16) STAGE(cur ^ 1, kc + 1);
        for (int kk = 0; kk < 2; ++kk) {
            bf16x8 a0 = *(const bf16x8*)&xs[cur][(wm * 32 + lid) * 72 + kk * 32 + quad * 8];
            bf16x8 a1 = *(const bf16x8*)&xs[cur][(wm * 32 + 16 + lid) * 72 + kk * 32 + quad * 8];
            const int swz = ((((kk << 2) | quad) ^ (lid & 7)) << 3);
            for (int nf = 0; nf < 3; ++nf) {
                const int n = wn * 48 + nf * 16 + lid;
                bf16x8 bfr = *(const bf16x8*)&ws[cur][n * 64 + swz];
                acc[0][nf] = __builtin_amdgcn_mfma_f32_16x16x32_bf16(a0, bfr, acc[0][nf], 0, 0, 0);
                acc[1][nf] = __builtin_amdgcn_mfma_f32_16x16x32_bf16(a1, bfr, acc[1][nf], 0, 0, 0);
            }
        }
        __syncthreads();
    }
#undef STAGE

    for (int mf = 0; mf < 2; ++mf)
        for (int nf = 0; nf < 3; ++nf) {
            const int col = wn * 48 + nf * 16 + lid;
            const int mid = col >> 6;      // 0=Q 1=K 2=V, uniform per (wn,nf)
            const int lc  = col & 63;
            const float bias = (mid == 0) ? bq[lc] : (mid == 1) ? bk[lc] : bv[lc];
            const int rb = row0 + wm * 32 + mf * 16 + quad * 4;   // + j
            f32x4 v = acc[mf][nf];
            if (mid < 2) {
                // frag-blocked Q/K: (s>>5)*2048 + (lc>>3)*256 + (s&31)*8 + (lc&7)
                const int base = ((rb >> 5) << 11) + ((lc >> 3) << 8)
                               + ((rb & 31) << 3) + (lc & 7);
                unsigned short* P = (mid == 0) ? Qp : Kp;
                const float sc = (mid == 0) ? QSCALE : 1.0f;
                for (int j = 0; j < 4; ++j)
                    P[base + j * 8] = f2bf((v[j] + bias) * sc);
            } else {
                // frag-blocked V: b*262144 + (s>>3)*512 + d*8 + (s&7); rb%4==0
                const int bb = rb >> 12, s = rb & 4095;
                ushort4 u;
                u.x = f2bf(v[0] + bias); u.y = f2bf(v[1] + bias);
                u.z = f2bf(v[2] + bias); u.w = f2bf(v[3] + bias);
                *(ushort4*)&Vt[bb * 262144 + (s >> 3) * 512 + lc * 8 + (s & 7)] = u;
            }
        }
}

// ---------------------------------------------------------------------------
// Kernel 2: MFMA flash attention (causal), swapped-QK^T 32x32 structure.
//   THIS ROUND: occupancy 2 -> 4 waves/SIMD.  1024 threads, 16-way k-split
//   within the block (same paired-q-tile balance: exactly 129 k-tiles per
//   block regardless of CU mapping).  Obuf grows to 16 slots (134 KB LDS,
//   still 1 block/CU -- which grid=256 forces anyway).  QK back to a single
//   4-deep MFMA chain: saves 16 VGPR so 4 waves/SIMD fit under the 128-VGPR
//   cap; its serial latency is now hidden by TLP instead of ILP.
// ---------------------------------------------------------------------------
__global__ __launch_bounds__(1024, 1) void flash_kernel(
    const unsigned short* __restrict__ Qp, const unsigned short* __restrict__ Kp,
    const unsigned short* __restrict__ Vt, float* __restrict__ out) {

    __shared__ __align__(16) float Obuf[16][32][66];  // 135.2 KB
    __shared__ float lbuf[16][32];                    // 2 KB

    const int tid  = threadIdx.x;
    const int lane = tid & 63;
    const int w    = tid >> 6;        // 0..15 (k-split index)
    const int hi   = lane >> 5;       // lane half (0/1)
    const int l5   = lane & 31;       // q-row within tile / d within half

    // 256 blocks: XCD = l&7 (batch pinned to XCD pair {b, b+4} for L2
    // locality), pair index p = (XCD>>2)*32 + (l>>3) in 0..63.
    const int l  = blockIdx.x;        // 0..255
    const int x  = l & 7;
    const int b  = x & 3;
    const int p  = ((x >> 2) << 5) + (l >> 3);

    const unsigned short* Kb = &Kp[b * 262144];   // b*128 s-blocks * 2048
    const unsigned short* Vb = &Vt[b * 262144];

    for (int half = 0; half < 2; ++half) {
        const int qt = half ? p : 127 - p;
        const int q0 = qt * 32;
        const int nt = qt + 1;        // 32-wide k tiles

        // Q as B-frags: lane l5 = q-row, 8 consecutive d per reg (dense load)
        bf16x8 qf[4];
#pragma unroll
        for (int dk = 0; dk < 4; ++dk)
            qf[dk] = *(const bf16x8*)&Qp[((b << 7) + qt) * 2048
                                         + (dk * 2 + hi) * 256 + l5 * 8];

        f32x16 O0 = {}, O1 = {};      // O[q][d], d-halves 0..31 / 32..63
        float ls = 0.f;               // row-sum partial (q = l5, own key-half)

        // prologue: K A-frags for first tile (dense)
        int t = w;
        bf16x8 kf[4];
        if (t < nt) {
#pragma unroll
            for (int dk = 0; dk < 4; ++dk)
                kf[dk] = *(const bf16x8*)&Kb[t * 2048 + (dk * 2 + hi) * 256 + l5 * 8];
        }

        while (t < nt) {
            const int kt = t << 5;
            // ---- V B-frags for this tile (dense): lane l5 = d, 8 keys/reg
            bf16x8 vf[2][2];
#pragma unroll
            for (int kc = 0; kc < 2; ++kc)
#pragma unroll
                for (int dh = 0; dh < 2; ++dh)
                    vf[dh][kc] = *(const bf16x8*)&Vb[(t * 4 + kc * 2 + hi) * 512
                                                     + (dh * 32 + l5) * 8];

            // ---- swapped QK^T (single 4-deep chain; latency hidden by TLP):
            //      st[rr] = S^T[key][q], key = kt+(rr&3)+8*(rr>>2)+4*hi, q=q0+l5
            __builtin_amdgcn_s_setprio(1);
            f32x16 st = {};
#pragma unroll
            for (int dk = 0; dk < 4; ++dk)
                st = __builtin_amdgcn_mfma_f32_32x32x16_bf16(kf[dk], qf[dk], st, 0, 0, 0);
            __builtin_amdgcn_s_setprio(0);

            // ---- prefetch K(t+16) (dense; hidden under softmax + PV)
            const int tn = t + 16;
            if (tn < nt) {
#pragma unroll
                for (int dk = 0; dk < 4; ++dk)
                    kf[dk] = *(const bf16x8*)&Kb[tn * 2048 + (dk * 2 + hi) * 256 + l5 * 8];
            }

            // ---- causal mask (diagonal tile only)
            if (t == nt - 1) {
#pragma unroll
                for (int rr = 0; rr < 16; ++rr) {
                    const int key = kt + (rr & 3) + 8 * (rr >> 2) + 4 * hi;
                    if (key > q0 + l5) st[rr] = -1e30f;
                }
            }

            // ---- exp2 + in-register P->bf16 A-frag (T12), fused with PV
#pragma unroll
            for (int kc = 0; kc < 2; ++kc) {
                const int c8 = kc * 8;
                float ev[8];
#pragma unroll
                for (int i = 0; i < 8; ++i) ev[i] = __builtin_amdgcn_exp2f(st[c8 + i]);
                ls += ((ev[0] + ev[1]) + (ev[2] + ev[3])) +
                      ((ev[4] + ev[5]) + (ev[6] + ev[7]));
                const int p0 = cvtpk_bf16(ev[0], ev[1]);
                const int p1 = cvtpk_bf16(ev[2], ev[3]);
                const int p2 = cvtpk_bf16(ev[4], ev[5]);
                const int p3 = cvtpk_bf16(ev[6], ev[7]);
                auto s02 = __builtin_amdgcn_permlane32_swap(p0, p2, false, false);
                auto s13 = __builtin_amdgcn_permlane32_swap(p1, p3, false, false);
                union { int wd[4]; bf16x8 v; } pf;
                pf.wd[0] = s02[0]; pf.wd[1] = s13[0];
                pf.wd[2] = s02[1]; pf.wd[3] = s13[1];
                __builtin_amdgcn_s_setprio(1);
                O0 = __builtin_amdgcn_mfma_f32_32x32x16_bf16(pf.v, vf[0][kc], O0, 0, 0, 0);
                O1 = __builtin_amdgcn_mfma_f32_32x32x16_bf16(pf.v, vf[1][kc], O1, 0, 0, 0);
                __builtin_amdgcn_s_setprio(0);
            }
            t = tn;
        }

        // ---- publish per-wave partials.  O C-layout: row(q)=(rr&3)+8*(rr>>2)+4*hi,
        //      col(d) = l5 (+32 for O1).  Lane-halves hold complementary
        //      key-halves for the same q -> one shfl_xor(32) for the row-sum.
        const float lt = ls + __shfl_xor(ls, 32);
#pragma unroll
        for (int rr = 0; rr < 16; ++rr) {
            const int row = (rr & 3) + 8 * (rr >> 2) + 4 * hi;
            Obuf[w][row][l5]      = O0[rr];
            Obuf[w][row][32 + l5] = O1[rr];
        }
        if (lane < 32) lbuf[w][l5] = lt;
        __syncthreads();

        // ---- combine: plain sums over 16 k-split partials; coalesced store
        const int col = tid & 63;
        const int r0  = tid >> 6;     // 0..15
        for (int ii = 0; ii < 2; ++ii) {
            const int row = r0 + ii * 16;
            float o = 0.f, lsum = 0.f;
            for (int ww = 0; ww < 16; ++ww) {
                o    += Obuf[ww][row][col];
                lsum += lbuf[ww][row];
            }
            out[(b * S_LEN + q0 + row) * 64 + col] = o / lsum;
        }
        __syncthreads();   // combine reads done before next half's publish
    }
}

// ---------------------------------------------------------------------------
extern "C" void kernel_launch(void* const* d_in, const int* in_sizes, int n_in,
                              void* d_out, int out_size, void* d_ws, size_t ws_size,
                              hipStream_t stream) {
    const float* x  = (const float*)d_in[0];
    const float* Wq = (const float*)d_in[1];
    const float* bq = (const float*)d_in[2];
    const float* Wk = (const float*)d_in[3];
    const float* bk = (const float*)d_in[4];
    const float* Wv = (const float*)d_in[5];
    const float* bv = (const float*)d_in[6];
    float* out = (float*)d_out;

    unsigned short* wt = (unsigned short*)d_ws;   // 16 chunks x 12288 shorts
    unsigned short* Qp = wt + 196608;             // 16384*64 each (blocked)
    unsigned short* Kp = Qp + 1048576;
    unsigned short* Vt = Kp + 1048576;            // [b][s/8][64][8] blocked

    hipLaunchKernelGGL(wprep_kernel, dim3(48), dim3(256), 0, stream, Wq, Wk, Wv, wt);
    hipLaunchKernelGGL(qkv_kernel, dim3(256), dim3(512), 0, stream,
                       x, wt, bq, bk, bv, Qp, Kp, Vt);
    hipLaunchKernelGGL(flash_kernel, dim3(256), dim3(1024), 0, stream,
                       Qp, Kp, Vt, out);
}

// Round 7
// 135.826 us; speedup vs baseline: 1.0301x; 1.0301x over previous
//
#include <hip/hip_runtime.h>
#include <stdint.h>

#define S_LEN 4096
#define EMB   1024
#define HEAD  64

typedef short bf16x8 __attribute__((ext_vector_type(8)));
typedef float f32x4  __attribute__((ext_vector_type(4)));
typedef float f32x16 __attribute__((ext_vector_type(16)));
typedef unsigned short ushort8 __attribute__((ext_vector_type(8)));

// scale = 1/sqrt(64) = 0.125, folded with log2(e) so softmax uses exp2
#define QSCALE 0.18033688011112042f

__device__ __forceinline__ unsigned short f2bf(float f) {
    union { float f; uint32_t u; } v; v.f = f;
    uint32_t r = v.u + 0x7fffu + ((v.u >> 16) & 1u);
    return (unsigned short)(r >> 16);
}

// pack two f32 -> one u32 of 2x bf16 (RNE), gfx950 HW op (no builtin)
__device__ __forceinline__ int cvtpk_bf16(float lo, float hi_) {
    int r;
    asm("v_cvt_pk_bf16_f32 %0, %1, %2" : "=v"(r) : "v"(lo), "v"(hi_));
    return r;
}

// async global->LDS, 16B per lane.  LDS dest is wave-uniform base + lane*16;
// global src is per-lane (m104).  size must be a literal.
__device__ __forceinline__ void gload_lds16(const void* g, void* l) {
    __builtin_amdgcn_global_load_lds(
        (const __attribute__((address_space(1))) void*)g,
        (__attribute__((address_space(3))) void*)l, 16, 0, 0);
}

// ---------------------------------------------------------------------------
// Fragment-blocked layouts (R4, kept -- the -19us win):
//   Qp/Kp : [s/32][8 d-chunks][32 rows][8 d]   (2048 shorts per s-block)
//   Vt    : [b][s/8][64 d][8 keys]             (512 shorts per s-group)
// Every flash-side fragment load is two dense 512B segments.
// ---------------------------------------------------------------------------

// ---------------------------------------------------------------------------
// Kernel 0: W prep (unchanged).  wt = 16 per-kchunk linear LDS images,
// XOR-swizzled for qkv's global_load_lds + swizzled ds_read_b128.
// ---------------------------------------------------------------------------
__global__ void wprep_kernel(const float* __restrict__ Wq,
                             const float* __restrict__ Wk,
                             const float* __restrict__ Wv,
                             unsigned short* __restrict__ wt) {
    __shared__ float t[64][65];
    const int tid = threadIdx.x;
    const int m   = blockIdx.x >> 4;
    const int kcb = blockIdx.x & 15;
    const int k0  = kcb << 6;
    const float* W = (m == 0) ? Wq : (m == 1) ? Wk : Wv;
    for (int i = 0; i < 4; ++i) {
        const int k  = (tid >> 4) + i * 16;
        const int n4 = (tid & 15) << 2;
        float4 v = *(const float4*)&W[(k0 + k) * 64 + n4];
        t[k][n4 + 0] = v.x; t[k][n4 + 1] = v.y;
        t[k][n4 + 2] = v.z; t[k][n4 + 3] = v.w;
    }
    __syncthreads();
    const int n = tid >> 2, kq = (tid & 3) << 4;   // 16 k-values per thread
    __align__(16) unsigned short u[16];
    for (int i = 0; i < 16; ++i) u[i] = f2bf(t[kq + i][n]);
    const int nimg = m * 64 + n;
    const int base = kcb * 12288 + nimg * 64;      // shorts
    const int c0   = (kq >> 3) ^ (n & 7);          // swizzled 16B-chunk idx
    const int c1   = ((kq >> 3) + 1) ^ (n & 7);
    *(int4*)&wt[base + c0 * 8] = *(int4*)&u[0];
    *(int4*)&wt[base + c1 * 8] = *(int4*)&u[8];
}

// ---------------------------------------------------------------------------
// Kernel 1: fused QKV projection, bf16 MFMA GEMM (R5 wave re-tile, kept:
// 2m x 4n, 10 ds_read_b128 per chunk vs 14).
// ---------------------------------------------------------------------------
__global__ __launch_bounds__(512, 2) void qkv_kernel(
    const float* __restrict__ x, const unsigned short* __restrict__ wt,
    const float* __restrict__ bq, const float* __restrict__ bk,
    const float* __restrict__ bv,
    unsigned short* __restrict__ Qp, unsigned short* __restrict__ Kp,
    unsigned short* __restrict__ Vt) {

    __shared__ __align__(16) unsigned short xs[2][64 * 72];   // 18.4 KB
    __shared__ __align__(16) unsigned short ws[2][12288];     // 49.2 KB

    const int tid  = threadIdx.x;
    const int lane = tid & 63;
    const int w    = tid >> 6;        // 0..7
    const int wm   = w & 1;           // 0..1  (32-row half)
    const int wn   = w >> 1;          // 0..3  (48-col strip)
    const int quad = lane >> 4;
    const int lid  = lane & 15;
    const int row0 = blockIdx.x * 64;

    f32x4 acc[2][3];
    for (int mf = 0; mf < 2; ++mf)
        for (int nf = 0; nf < 3; ++nf) acc[mf][nf] = (f32x4){0.f, 0.f, 0.f, 0.f};

#define STAGE(BUF, KC)                                                         \
    do {                                                                       \
        {   /* x: 64 rows x 64 k fp32 -> bf16, 8 floats per thread */          \
            int rr = tid >> 3, c8 = (tid & 7) << 3;                            \
            const float* xp = &x[(row0 + rr) * EMB + (KC) * 64 + c8];          \
            float4 v0 = *(const float4*)xp;                                    \
            float4 v1 = *(const float4*)(xp + 4);                              \
            ushort8 u;                                                         \
            u[0] = f2bf(v0.x); u[1] = f2bf(v0.y);                              \
            u[2] = f2bf(v0.z); u[3] = f2bf(v0.w);                              \
            u[4] = f2bf(v1.x); u[5] = f2bf(v1.y);                              \
            u[6] = f2bf(v1.z); u[7] = f2bf(v1.w);                              \
            *(ushort8*)&xs[BUF][rr * 72 + c8] = u;                             \
        }                                                                      \
        {   /* wt chunk: 24.6 KB linear swizzled image, 3 KB per wave */       \
            const unsigned short* gs = &wt[(KC) * 12288 + w * 1536 + lane * 8];\
            gload_lds16(gs,        &ws[BUF][w * 1536]);                        \
            gload_lds16(gs +  512, &ws[BUF][w * 1536 +  512]);                 \
            gload_lds16(gs + 1024, &ws[BUF][w * 1536 + 1024]);                 \
        }                                                                      \
    } while (0)

    STAGE(0, 0);
    __syncthreads();

    for (int kc = 0; kc < 16; ++kc) {
        const int cur = kc & 1;
        if (kc + 1 < 16) STAGE(cur ^ 1, kc + 1);
        for (int kk = 0; kk < 2; ++kk) {
            bf16x8 a0 = *(const bf16x8*)&xs[cur][(wm * 32 + lid) * 72 + kk * 32 + quad * 8];
            bf16x8 a1 = *(const bf16x8*)&xs[cur][(wm * 32 + 16 + lid) * 72 + kk * 32 + quad * 8];
            const int swz = ((((kk << 2) | quad) ^ (lid & 7)) << 3);
            for (int nf = 0; nf < 3; ++nf) {
                const int n = wn * 48 + nf * 16 + lid;
                bf16x8 bfr = *(const bf16x8*)&ws[cur][n * 64 + swz];
                acc[0][nf] = __builtin_amdgcn_mfma_f32_16x16x32_bf16(a0, bfr, acc[0][nf], 0, 0, 0);
                acc[1][nf] = __builtin_amdgcn_mfma_f32_16x16x32_bf16(a1, bfr, acc[1][nf], 0, 0, 0);
            }
        }
        __syncthreads();
    }
#undef STAGE

    for (int mf = 0; mf < 2; ++mf)
        for (int nf = 0; nf < 3; ++nf) {
            const int col = wn * 48 + nf * 16 + lid;
            const int mid = col >> 6;      // 0=Q 1=K 2=V, uniform per (wn,nf)
            const int lc  = col & 63;
            const float bias = (mid == 0) ? bq[lc] : (mid == 1) ? bk[lc] : bv[lc];
            const int rb = row0 + wm * 32 + mf * 16 + quad * 4;   // + j
            f32x4 v = acc[mf][nf];
            if (mid < 2) {
                // frag-blocked Q/K: (s>>5)*2048 + (lc>>3)*256 + (s&31)*8 + (lc&7)
                const int base = ((rb >> 5) << 11) + ((lc >> 3) << 8)
                               + ((rb & 31) << 3) + (lc & 7);
                unsigned short* P = (mid == 0) ? Qp : Kp;
                const float sc = (mid == 0) ? QSCALE : 1.0f;
                for (int j = 0; j < 4; ++j)
                    P[base + j * 8] = f2bf((v[j] + bias) * sc);
            } else {
                // frag-blocked V: b*262144 + (s>>3)*512 + d*8 + (s&7); rb%4==0
                const int bb = rb >> 12, s = rb & 4095;
                ushort4 u;
                u.x = f2bf(v[0] + bias); u.y = f2bf(v[1] + bias);
                u.z = f2bf(v[2] + bias); u.w = f2bf(v[3] + bias);
                *(ushort4*)&Vt[bb * 262144 + (s >> 3) * 512 + lc * 8 + (s & 7)] = u;
            }
        }
}

// ---------------------------------------------------------------------------
// flash helpers (all indices compile-time in unrolled loops -- rule #20)
// ---------------------------------------------------------------------------
__device__ __forceinline__ void load_k(const unsigned short* Kb, int t,
                                       int hi, int l5, bf16x8 (&kf)[4]) {
#pragma unroll
    for (int dk = 0; dk < 4; ++dk)
        kf[dk] = *(const bf16x8*)&Kb[t * 2048 + (dk * 2 + hi) * 256 + l5 * 8];
}

__device__ __forceinline__ void load_v(const unsigned short* Vb, int t,
                                       int hi, int l5, bf16x8 (&vf)[2][2]) {
#pragma unroll
    for (int kc = 0; kc < 2; ++kc)
#pragma unroll
        for (int dh = 0; dh < 2; ++dh)
            vf[dh][kc] = *(const bf16x8*)&Vb[(t * 4 + kc * 2 + hi) * 512
                                             + (dh * 32 + l5) * 8];
}

__device__ __forceinline__ void mask_diag(f32x16& st, int kt, int q0,
                                          int hi, int l5) {
#pragma unroll
    for (int rr = 0; rr < 16; ++rr) {
        const int key = kt + (rr & 3) + 8 * (rr >> 2) + 4 * hi;
        if (key > q0 + l5) st[rr] = -1e30f;
    }
}

__device__ __forceinline__ void softmax_pv(const f32x16& st, const bf16x8 (&vf)[2][2],
                                           f32x16& O0, f32x16& O1, float& ls) {
#pragma unroll
    for (int kc = 0; kc < 2; ++kc) {
        const int c8 = kc * 8;
        float ev[8];
#pragma unroll
        for (int i = 0; i < 8; ++i) ev[i] = __builtin_amdgcn_exp2f(st[c8 + i]);
        ls += ((ev[0] + ev[1]) + (ev[2] + ev[3])) +
              ((ev[4] + ev[5]) + (ev[6] + ev[7]));
        const int p0 = cvtpk_bf16(ev[0], ev[1]);
        const int p1 = cvtpk_bf16(ev[2], ev[3]);
        const int p2 = cvtpk_bf16(ev[4], ev[5]);
        const int p3 = cvtpk_bf16(ev[6], ev[7]);
        auto s02 = __builtin_amdgcn_permlane32_swap(p0, p2, false, false);
        auto s13 = __builtin_amdgcn_permlane32_swap(p1, p3, false, false);
        union { int wd[4]; bf16x8 v; } pf;
        pf.wd[0] = s02[0]; pf.wd[1] = s13[0];
        pf.wd[2] = s02[1]; pf.wd[3] = s13[1];
        __builtin_amdgcn_s_setprio(1);
        O0 = __builtin_amdgcn_mfma_f32_32x32x16_bf16(pf.v, vf[0][kc], O0, 0, 0, 0);
        O1 = __builtin_amdgcn_mfma_f32_32x32x16_bf16(pf.v, vf[1][kc], O1, 0, 0, 0);
        __builtin_amdgcn_s_setprio(0);
    }
}

// ---------------------------------------------------------------------------
// Kernel 2: MFMA flash attention (causal), swapped-QK^T 32x32 structure.
//   R4 occupancy shape restored (8 waves, 512 thr, (512,1) -> 256-VGPR cap,
//   67.6 KB LDS; R5's 16-wave version hit the 128-VGPR spill cliff).
//   THIS ROUND: TWO k-tiles per iteration (t, t+8; stride 16) -- two
//   independent QK->softmax->PV chains per wave double ILP at 2 waves/SIMD
//   without raising occupancy or the register cap (peak ~190 < 256).
//   PV accumulation order into O is unchanged (t, t+8, t+16, ...).
//   Paired-q-tile balance / mask / publish / combine(8): R4-verbatim.
// ---------------------------------------------------------------------------
__global__ __launch_bounds__(512, 1) void flash_kernel(
    const unsigned short* __restrict__ Qp, const unsigned short* __restrict__ Kp,
    const unsigned short* __restrict__ Vt, float* __restrict__ out) {

    __shared__ __align__(16) float Obuf[8][32][66];   // 67.6 KB
    __shared__ float lbuf[8][32];                     // 1 KB

    const int tid  = threadIdx.x;
    const int lane = tid & 63;
    const int w    = tid >> 6;        // 0..7 (k-split index)
    const int hi   = lane >> 5;       // lane half (0/1)
    const int l5   = lane & 31;       // q-row within tile / d within half

    // 256 blocks: XCD = l&7 (batch pinned to XCD pair {b, b+4} for L2
    // locality), pair index p = (XCD>>2)*32 + (l>>3) in 0..63.
    const int l  = blockIdx.x;        // 0..255
    const int x  = l & 7;
    const int b  = x & 3;
    const int p  = ((x >> 2) << 5) + (l >> 3);

    const unsigned short* Kb = &Kp[b * 262144];   // b*128 s-blocks * 2048
    const unsigned short* Vb = &Vt[b * 262144];

    for (int half = 0; half < 2; ++half) {
        const int qt = half ? p : 127 - p;
        const int q0 = qt * 32;
        const int nt = qt + 1;        // 32-wide k tiles

        // Q as B-frags: lane l5 = q-row, 8 consecutive d per reg (dense load)
        bf16x8 qf[4];
#pragma unroll
        for (int dk = 0; dk < 4; ++dk)
            qf[dk] = *(const bf16x8*)&Qp[((b << 7) + qt) * 2048
                                         + (dk * 2 + hi) * 256 + l5 * 8];

        f32x16 O0 = {}, O1 = {};      // O[q][d], d-halves 0..31 / 32..63
        float ls = 0.f;               // row-sum partial (q = l5, own key-half)

        // prologue: K frags for this wave's first tile pair
        int t = w;
        bf16x8 kf1[4], kf2[4];
        if (t < nt)     load_k(Kb, t,     hi, l5, kf1);
        if (t + 8 < nt) load_k(Kb, t + 8, hi, l5, kf2);

        while (t < nt) {
            const int t2   = t + 8;
            const bool has2 = (t2 < nt);

            // ---- tile-1: V loads then QK (vf1 lands under QK+softmax)
            bf16x8 vf1[2][2];
            load_v(Vb, t, hi, l5, vf1);
            __builtin_amdgcn_s_setprio(1);
            f32x16 st1 = {};
#pragma unroll
            for (int dk = 0; dk < 4; ++dk)
                st1 = __builtin_amdgcn_mfma_f32_32x32x16_bf16(kf1[dk], qf[dk], st1, 0, 0, 0);
            __builtin_amdgcn_s_setprio(0);

            // ---- tile-2: independent chain, overlaps tile-1's softmax/PV
            bf16x8 vf2[2][2];
            f32x16 st2 = {};
            if (has2) {
                load_v(Vb, t2, hi, l5, vf2);
                __builtin_amdgcn_s_setprio(1);
#pragma unroll
                for (int dk = 0; dk < 4; ++dk)
                    st2 = __builtin_amdgcn_mfma_f32_32x32x16_bf16(kf2[dk], qf[dk], st2, 0, 0, 0);
                __builtin_amdgcn_s_setprio(0);
            }

            // ---- prefetch next pair's K (hidden under softmax + PV)
            if (t + 16 < nt) load_k(Kb, t + 16, hi, l5, kf1);
            if (t + 24 < nt) load_k(Kb, t + 24, hi, l5, kf2);

            // ---- softmax + PV, tile-1 then tile-2 (O order = R4)
            if (t == nt - 1) mask_diag(st1, t << 5, q0, hi, l5);
            softmax_pv(st1, vf1, O0, O1, ls);
            if (has2) {
                if (t2 == nt - 1) mask_diag(st2, t2 << 5, q0, hi, l5);
                softmax_pv(st2, vf2, O0, O1, ls);
            }
            t += 16;
        }

        // ---- publish per-wave partials.  O C-layout: row(q)=(rr&3)+8*(rr>>2)+4*hi,
        //      col(d) = l5 (+32 for O1).  Lane-halves hold complementary
        //      key-halves for the same q -> one shfl_xor(32) for the row-sum.
        const float lt = ls + __shfl_xor(ls, 32);
#pragma unroll
        for (int rr = 0; rr < 16; ++rr) {
            const int row = (rr & 3) + 8 * (rr >> 2) + 4 * hi;
            Obuf[w][row][l5]      = O0[rr];
            Obuf[w][row][32 + l5] = O1[rr];
        }
        if (lane < 32) lbuf[w][l5] = lt;
        __syncthreads();

        // ---- combine: plain sums over 8 k-split partials; coalesced store
        const int col = tid & 63;
        const int r0  = tid >> 6;
        for (int ii = 0; ii < 4; ++ii) {
            const int row = r0 + ii * 8;
            float o = 0.f, lsum = 0.f;
            for (int ww = 0; ww < 8; ++ww) {
                o    += Obuf[ww][row][col];
                lsum += lbuf[ww][row];
            }
            out[(b * S_LEN + q0 + row) * 64 + col] = o / lsum;
        }
        __syncthreads();   // combine reads done before next half's publish
    }
}

// ---------------------------------------------------------------------------
extern "C" void kernel_launch(void* const* d_in, const int* in_sizes, int n_in,
                              void* d_out, int out_size, void* d_ws, size_t ws_size,
                              hipStream_t stream) {
    const float* x  = (const float*)d_in[0];
    const float* Wq = (const float*)d_in[1];
    const float* bq = (const float*)d_in[2];
    const float* Wk = (const float*)d_in[3];
    const float* bk = (const float*)d_in[4];
    const float* Wv = (const float*)d_in[5];
    const float* bv = (const float*)d_in[6];
    float* out = (float*)d_out;

    unsigned short* wt = (unsigned short*)d_ws;   // 16 chunks x 12288 shorts
    unsigned short* Qp = wt + 196608;             // 16384*64 each (blocked)
    unsigned short* Kp = Qp + 1048576;
    unsigned short* Vt = Kp + 1048576;            // [b][s/8][64][8] blocked

    hipLaunchKernelGGL(wprep_kernel, dim3(48), dim3(256), 0, stream, Wq, Wk, Wv, wt);
    hipLaunchKernelGGL(qkv_kernel, dim3(256), dim3(512), 0, stream,
                       x, wt, bq, bk, bv, Qp, Kp, Vt);
    hipLaunchKernelGGL(flash_kernel, dim3(256), dim3(512), 0, stream,
                       Qp, Kp, Vt, out);
}

// Round 8
// 131.179 us; speedup vs baseline: 1.0666x; 1.0354x over previous
//
#include <hip/hip_runtime.h>
#include <stdint.h>

#define S_LEN 4096
#define EMB   1024
#define HEAD  64

typedef short bf16x8 __attribute__((ext_vector_type(8)));
typedef float f32x4  __attribute__((ext_vector_type(4)));
typedef float f32x16 __attribute__((ext_vector_type(16)));

// scale = 1/sqrt(64) = 0.125, folded with log2(e) so softmax uses exp2
#define QSCALE 0.18033688011112042f

__device__ __forceinline__ unsigned short f2bf(float f) {
    union { float f; uint32_t u; } v; v.f = f;
    uint32_t r = v.u + 0x7fffu + ((v.u >> 16) & 1u);
    return (unsigned short)(r >> 16);
}

// pack two f32 -> one u32 of 2x bf16 (RNE), gfx950 HW op (no builtin)
__device__ __forceinline__ int cvtpk_bf16(float lo, float hi_) {
    int r;
    asm("v_cvt_pk_bf16_f32 %0, %1, %2" : "=v"(r) : "v"(lo), "v"(hi_));
    return r;
}

// async global->LDS, 16B per lane.  LDS dest is wave-uniform base + lane*16;
// global src is per-lane (m104).  size must be a literal.
__device__ __forceinline__ void gload_lds16(const void* g, void* l) {
    __builtin_amdgcn_global_load_lds(
        (const __attribute__((address_space(1))) void*)g,
        (__attribute__((address_space(3))) void*)l, 16, 0, 0);
}

// ---------------------------------------------------------------------------
// Fragment-blocked layouts (R4, kept -- the -19us win):
//   Qp/Kp : [s/32][8 d-chunks][32 rows][8 d]   (2048 shorts per s-block)
//   Vt    : [b][s/8][64 d][8 keys]             (512 shorts per s-group)
// Every flash-side fragment load is two dense 512B segments.
// ---------------------------------------------------------------------------

// ---------------------------------------------------------------------------
// Kernel 0: W prep (unchanged).  wt = 16 per-kchunk linear LDS images,
// XOR-swizzled for qkv's global_load_lds + swizzled ds_read_b128.
// ---------------------------------------------------------------------------
__global__ void wprep_kernel(const float* __restrict__ Wq,
                             const float* __restrict__ Wk,
                             const float* __restrict__ Wv,
                             unsigned short* __restrict__ wt) {
    __shared__ float t[64][65];
    const int tid = threadIdx.x;
    const int m   = blockIdx.x >> 4;
    const int kcb = blockIdx.x & 15;
    const int k0  = kcb << 6;
    const float* W = (m == 0) ? Wq : (m == 1) ? Wk : Wv;
    for (int i = 0; i < 4; ++i) {
        const int k  = (tid >> 4) + i * 16;
        const int n4 = (tid & 15) << 2;
        float4 v = *(const float4*)&W[(k0 + k) * 64 + n4];
        t[k][n4 + 0] = v.x; t[k][n4 + 1] = v.y;
        t[k][n4 + 2] = v.z; t[k][n4 + 3] = v.w;
    }
    __syncthreads();
    const int n = tid >> 2, kq = (tid & 3) << 4;   // 16 k-values per thread
    __align__(16) unsigned short u[16];
    for (int i = 0; i < 16; ++i) u[i] = f2bf(t[kq + i][n]);
    const int nimg = m * 64 + n;
    const int base = kcb * 12288 + nimg * 64;      // shorts
    const int c0   = (kq >> 3) ^ (n & 7);          // swizzled 16B-chunk idx
    const int c1   = ((kq >> 3) + 1) ^ (n & 7);
    *(int4*)&wt[base + c0 * 8] = *(int4*)&u[0];
    *(int4*)&wt[base + c1 * 8] = *(int4*)&u[8];
}

// ---------------------------------------------------------------------------
// Kernel 1: fused QKV projection, bf16 MFMA GEMM.
//   THIS ROUND: grid 512 x 32-row tiles (was 256 x 64).  256 blocks = 1
//   block/CU left the stage->vmcnt(0)->barrier drain (~900cy HBM latency vs
//   ~200cy compute/chunk) unhidden; 2 co-resident blocks (LDS 58.4KB x 2 =
//   117KB < 160KB) overlap each other's drains.  Keeps: global_load_lds W
//   staging from pre-swizzled wt, swizzled ds_read_b128, blocked epilogue.
//   Per-wave tile 16 rows x 48 cols: 1 A + 3 B reads per kk, 3 acc.
// ---------------------------------------------------------------------------
__global__ __launch_bounds__(512, 2) void qkv_kernel(
    const float* __restrict__ x, const unsigned short* __restrict__ wt,
    const float* __restrict__ bq, const float* __restrict__ bk,
    const float* __restrict__ bv,
    unsigned short* __restrict__ Qp, unsigned short* __restrict__ Kp,
    unsigned short* __restrict__ Vt) {

    __shared__ __align__(16) unsigned short xs[2][32 * 72];   // 9.2 KB
    __shared__ __align__(16) unsigned short ws[2][12288];     // 49.2 KB

    const int tid  = threadIdx.x;
    const int lane = tid & 63;
    const int w    = tid >> 6;        // 0..7
    const int wm   = w & 1;           // 0..1  (16-row half)
    const int wn   = w >> 1;          // 0..3  (48-col strip)
    const int quad = lane >> 4;
    const int lid  = lane & 15;
    const int row0 = blockIdx.x * 32;

    f32x4 acc[3];
    for (int nf = 0; nf < 3; ++nf) acc[nf] = (f32x4){0.f, 0.f, 0.f, 0.f};

#define STAGE(BUF, KC)                                                         \
    do {                                                                       \
        {   /* x: 32 rows x 64 k fp32 -> bf16, one float4 per thread */        \
            int rr = tid >> 4, c4 = (tid & 15) << 2;                           \
            float4 v = *(const float4*)&x[(row0 + rr) * EMB + (KC) * 64 + c4]; \
            ushort4 u;                                                         \
            u.x = f2bf(v.x); u.y = f2bf(v.y); u.z = f2bf(v.z); u.w = f2bf(v.w);\
            *(ushort4*)&xs[BUF][rr * 72 + c4] = u;                             \
        }                                                                      \
        {   /* wt chunk: 24.6 KB linear swizzled image, 3 KB per wave */       \
            const unsigned short* gs = &wt[(KC) * 12288 + w * 1536 + lane * 8];\
            gload_lds16(gs,        &ws[BUF][w * 1536]);                        \
            gload_lds16(gs +  512, &ws[BUF][w * 1536 +  512]);                 \
            gload_lds16(gs + 1024, &ws[BUF][w * 1536 + 1024]);                 \
        }                                                                      \
    } while (0)

    STAGE(0, 0);
    __syncthreads();

    for (int kc = 0; kc < 16; ++kc) {
        const int cur = kc & 1;
        if (kc + 1 < 16) STAGE(cur ^ 1, kc + 1);
        for (int kk = 0; kk < 2; ++kk) {
            bf16x8 a = *(const bf16x8*)&xs[cur][(wm * 16 + lid) * 72 + kk * 32 + quad * 8];
            const int swz = ((((kk << 2) | quad) ^ (lid & 7)) << 3);
            for (int nf = 0; nf < 3; ++nf) {
                const int n = wn * 48 + nf * 16 + lid;
                bf16x8 bfr = *(const bf16x8*)&ws[cur][n * 64 + swz];
                acc[nf] = __builtin_amdgcn_mfma_f32_16x16x32_bf16(a, bfr, acc[nf], 0, 0, 0);
            }
        }
        __syncthreads();
    }
#undef STAGE

    for (int nf = 0; nf < 3; ++nf) {
        const int col = wn * 48 + nf * 16 + lid;
        const int mid = col >> 6;          // 0=Q 1=K 2=V, uniform per (wn,nf)
        const int lc  = col & 63;
        const float bias = (mid == 0) ? bq[lc] : (mid == 1) ? bk[lc] : bv[lc];
        const int rb = row0 + wm * 16 + quad * 4;   // + j
        f32x4 v = acc[nf];
        if (mid < 2) {
            // frag-blocked Q/K: (s>>5)*2048 + (lc>>3)*256 + (s&31)*8 + (lc&7)
            const int base = ((rb >> 5) << 11) + ((lc >> 3) << 8)
                           + ((rb & 31) << 3) + (lc & 7);
            unsigned short* P = (mid == 0) ? Qp : Kp;
            const float sc = (mid == 0) ? QSCALE : 1.0f;
            for (int j = 0; j < 4; ++j)
                P[base + j * 8] = f2bf((v[j] + bias) * sc);
        } else {
            // frag-blocked V: b*262144 + (s>>3)*512 + d*8 + (s&7); rb%4==0
            const int bb = rb >> 12, s = rb & 4095;
            ushort4 u;
            u.x = f2bf(v[0] + bias); u.y = f2bf(v[1] + bias);
            u.z = f2bf(v[2] + bias); u.w = f2bf(v[3] + bias);
            *(ushort4*)&Vt[bb * 262144 + (s >> 3) * 512 + lc * 8 + (s & 7)] = u;
        }
    }
}

// ---------------------------------------------------------------------------
// Kernel 2: MFMA flash attention (causal), swapped-QK^T 32x32 structure.
//   R4-VERBATIM (best verified: 133.0 us).  8 waves, 512 thr, (512,1) ->
//   256-VGPR cap, 67.6 KB LDS.  Paired q-tiles (127-p, p): exactly 129
//   k-tiles per block regardless of CU mapping.  Dual 2-deep QK chains.
//   R5's 16-wave TLP (spill cliff) and R6/R7's 2-tile ILP (null/negative)
//   are both reverted.
// ---------------------------------------------------------------------------
__global__ __launch_bounds__(512, 1) void flash_kernel(
    const unsigned short* __restrict__ Qp, const unsigned short* __restrict__ Kp,
    const unsigned short* __restrict__ Vt, float* __restrict__ out) {

    __shared__ __align__(16) float Obuf[8][32][66];   // 67.6 KB
    __shared__ float lbuf[8][32];                     // 1 KB

    const int tid  = threadIdx.x;
    const int lane = tid & 63;
    const int w    = tid >> 6;        // 0..7 (k-split index)
    const int hi   = lane >> 5;       // lane half (0/1)
    const int l5   = lane & 31;       // q-row within tile / d within half

    // 256 blocks: XCD = l&7 (batch pinned to XCD pair {b, b+4} for L2
    // locality), pair index p = (XCD>>2)*32 + (l>>3) in 0..63.
    const int l  = blockIdx.x;        // 0..255
    const int x  = l & 7;
    const int b  = x & 3;
    const int p  = ((x >> 2) << 5) + (l >> 3);

    const unsigned short* Kb = &Kp[b * 262144];   // b*128 s-blocks * 2048
    const unsigned short* Vb = &Vt[b * 262144];

    for (int half = 0; half < 2; ++half) {
        const int qt = half ? p : 127 - p;
        const int q0 = qt * 32;
        const int nt = qt + 1;        // 32-wide k tiles

        // Q as B-frags: lane l5 = q-row, 8 consecutive d per reg (dense load)
        bf16x8 qf[4];
#pragma unroll
        for (int dk = 0; dk < 4; ++dk)
            qf[dk] = *(const bf16x8*)&Qp[((b << 7) + qt) * 2048
                                         + (dk * 2 + hi) * 256 + l5 * 8];

        f32x16 O0 = {}, O1 = {};      // O[q][d], d-halves 0..31 / 32..63
        float ls = 0.f;               // row-sum partial (q = l5, own key-half)

        // prologue: K A-frags for first tile (dense)
        int t = w;
        bf16x8 kf[4];
        if (t < nt) {
#pragma unroll
            for (int dk = 0; dk < 4; ++dk)
                kf[dk] = *(const bf16x8*)&Kb[t * 2048 + (dk * 2 + hi) * 256 + l5 * 8];
        }

        while (t < nt) {
            const int kt = t << 5;
            // ---- V B-frags for this tile (dense): lane l5 = d, 8 keys/reg
            bf16x8 vf[2][2];
#pragma unroll
            for (int kc = 0; kc < 2; ++kc)
#pragma unroll
                for (int dh = 0; dh < 2; ++dh)
                    vf[dh][kc] = *(const bf16x8*)&Vb[(t * 4 + kc * 2 + hi) * 512
                                                     + (dh * 32 + l5) * 8];

            // ---- swapped QK^T, two independent 2-deep chains:
            //      st[rr] = S^T[key][q], key = kt+(rr&3)+8*(rr>>2)+4*hi, q = q0+l5
            __builtin_amdgcn_s_setprio(1);
            f32x16 sa = {}, sb = {};
            sa = __builtin_amdgcn_mfma_f32_32x32x16_bf16(kf[0], qf[0], sa, 0, 0, 0);
            sb = __builtin_amdgcn_mfma_f32_32x32x16_bf16(kf[1], qf[1], sb, 0, 0, 0);
            sa = __builtin_amdgcn_mfma_f32_32x32x16_bf16(kf[2], qf[2], sa, 0, 0, 0);
            sb = __builtin_amdgcn_mfma_f32_32x32x16_bf16(kf[3], qf[3], sb, 0, 0, 0);
            __builtin_amdgcn_s_setprio(0);

            // ---- prefetch K(t+8) (dense; hidden under softmax + PV)
            const int tn = t + 8;
            if (tn < nt) {
#pragma unroll
                for (int dk = 0; dk < 4; ++dk)
                    kf[dk] = *(const bf16x8*)&Kb[tn * 2048 + (dk * 2 + hi) * 256 + l5 * 8];
            }

            f32x16 st = sa + sb;

            // ---- causal mask (diagonal tile only)
            if (t == nt - 1) {
#pragma unroll
                for (int rr = 0; rr < 16; ++rr) {
                    const int key = kt + (rr & 3) + 8 * (rr >> 2) + 4 * hi;
                    if (key > q0 + l5) st[rr] = -1e30f;
                }
            }

            // ---- exp2 + in-register P->bf16 A-frag (T12), fused with PV
#pragma unroll
            for (int kc = 0; kc < 2; ++kc) {
                const int c8 = kc * 8;
                float ev[8];
#pragma unroll
                for (int i = 0; i < 8; ++i) ev[i] = __builtin_amdgcn_exp2f(st[c8 + i]);
                ls += ((ev[0] + ev[1]) + (ev[2] + ev[3])) +
                      ((ev[4] + ev[5]) + (ev[6] + ev[7]));
                const int p0 = cvtpk_bf16(ev[0], ev[1]);
                const int p1 = cvtpk_bf16(ev[2], ev[3]);
                const int p2 = cvtpk_bf16(ev[4], ev[5]);
                const int p3 = cvtpk_bf16(ev[6], ev[7]);
                auto s02 = __builtin_amdgcn_permlane32_swap(p0, p2, false, false);
                auto s13 = __builtin_amdgcn_permlane32_swap(p1, p3, false, false);
                union { int wd[4]; bf16x8 v; } pf;
                pf.wd[0] = s02[0]; pf.wd[1] = s13[0];
                pf.wd[2] = s02[1]; pf.wd[3] = s13[1];
                __builtin_amdgcn_s_setprio(1);
                O0 = __builtin_amdgcn_mfma_f32_32x32x16_bf16(pf.v, vf[0][kc], O0, 0, 0, 0);
                O1 = __builtin_amdgcn_mfma_f32_32x32x16_bf16(pf.v, vf[1][kc], O1, 0, 0, 0);
                __builtin_amdgcn_s_setprio(0);
            }
            t = tn;
        }

        // ---- publish per-wave partials.  O C-layout: row(q)=(rr&3)+8*(rr>>2)+4*hi,
        //      col(d) = l5 (+32 for O1).  Lane-halves hold complementary
        //      key-halves for the same q -> one shfl_xor(32) for the row-sum.
        const float lt = ls + __shfl_xor(ls, 32);
#pragma unroll
        for (int rr = 0; rr < 16; ++rr) {
            const int row = (rr & 3) + 8 * (rr >> 2) + 4 * hi;
            Obuf[w][row][l5]      = O0[rr];
            Obuf[w][row][32 + l5] = O1[rr];
        }
        if (lane < 32) lbuf[w][l5] = lt;
        __syncthreads();

        // ---- combine: plain sums over 8 k-split partials; coalesced store
        const int col = tid & 63;
        const int r0  = tid >> 6;
        for (int ii = 0; ii < 4; ++ii) {
            const int row = r0 + ii * 8;
            float o = 0.f, lsum = 0.f;
            for (int ww = 0; ww < 8; ++ww) {
                o    += Obuf[ww][row][col];
                lsum += lbuf[ww][row];
            }
            out[(b * S_LEN + q0 + row) * 64 + col] = o / lsum;
        }
        __syncthreads();   // combine reads done before next half's publish
    }
}

// ---------------------------------------------------------------------------
extern "C" void kernel_launch(void* const* d_in, const int* in_sizes, int n_in,
                              void* d_out, int out_size, void* d_ws, size_t ws_size,
                              hipStream_t stream) {
    const float* x  = (const float*)d_in[0];
    const float* Wq = (const float*)d_in[1];
    const float* bq = (const float*)d_in[2];
    const float* Wk = (const float*)d_in[3];
    const float* bk = (const float*)d_in[4];
    const float* Wv = (const float*)d_in[5];
    const float* bv = (const float*)d_in[6];
    float* out = (float*)d_out;

    unsigned short* wt = (unsigned short*)d_ws;   // 16 chunks x 12288 shorts
    unsigned short* Qp = wt + 196608;             // 16384*64 each (blocked)
    unsigned short* Kp = Qp + 1048576;
    unsigned short* Vt = Kp + 1048576;            // [b][s/8][64][8] blocked

    hipLaunchKernelGGL(wprep_kernel, dim3(48), dim3(256), 0, stream, Wq, Wk, Wv, wt);
    hipLaunchKernelGGL(qkv_kernel, dim3(512), dim3(512), 0, stream,
                       x, wt, bq, bk, bv, Qp, Kp, Vt);
    hipLaunchKernelGGL(flash_kernel, dim3(256), dim3(512), 0, stream,
                       Qp, Kp, Vt, out);
}